// Round 14
// baseline (3189.200 us; speedup 1.0000x reference)
//
#include <hip/hip_runtime.h>
#include <hip/hip_bf16.h>

// Problem constants
#define B_    64
#define T_    512
#define I_    256
#define H_    1024
#define KSTEPS 40          // (I_+H_)/32 slices
#define NGRP  4            // batch groups of 16 real rows
#define BG    16           // batch rows per group
#define RPG   64           // ranks (WGs) per group
#define NWG   256          // total recurrence WGs

typedef __bf16 bf16x8 __attribute__((ext_vector_type(8)));
typedef float  f32x4  __attribute__((ext_vector_type(4)));

__device__ __forceinline__ unsigned short f2bf(float f) {
  unsigned u = __builtin_bit_cast(unsigned, f);
  u += 0x7FFFu + ((u >> 16) & 1u);       // round-to-nearest-even
  return (unsigned short)(u >> 16);
}
__device__ __forceinline__ float sigm(float x) { return 1.0f / (1.0f + __expf(-x)); }
__device__ __forceinline__ float tanh_fast(float x) {
  float ax = fabsf(x);
  float e  = __expf(-2.0f * ax);
  float t  = (1.0f - e) / (1.0f + e);
  return x < 0.0f ? -t : t;
}

// ---------------- K0: x [B,T,I] f32 -> xb [T,B,I] bf16 ----------------
__global__ void k_pack_x(const float* __restrict__ x, unsigned short* __restrict__ xb) {
  int idx = blockIdx.x * blockDim.x + threadIdx.x;   // B*T*I/8 = 1,048,576
  int ic = idx & 31;
  int t  = (idx >> 5) & 511;
  int b  = idx >> 14;
  const float* src = x + ((size_t)b * T_ + t) * I_ + ic * 8;
  float4 f0 = *(const float4*)src;
  float4 f1 = *(const float4*)(src + 4);
  unsigned short o[8] = {f2bf(f0.x), f2bf(f0.y), f2bf(f0.z), f2bf(f0.w),
                         f2bf(f1.x), f2bf(f1.y), f2bf(f1.z), f2bf(f1.w)};
  *(uint4*)(xb + ((size_t)t * B_ + b) * I_ + ic * 8) = *(uint4*)o;
}

// ---------------- K1a: pack W into per-(rank,gate) B-fragment layout ----------------
// rank r (0..63) owns gate-cols [r*16, r*16+16) in each of 4 gates.
// layout: [((r*4+gt)*40 + kk)*64 + lane] (16B frag); col n = lane&15,
// W row = gt*H + r*16 + n, k = kk*32 + (lane>>4)*8 + e  (k<256 -> W_ih).
__global__ void k_pack_w(const float* __restrict__ Wih, const float* __restrict__ Whh,
                         const float* __restrict__ bih, const float* __restrict__ bhh,
                         unsigned short* __restrict__ wpack, float* __restrict__ biasp) {
  int f = blockIdx.x * blockDim.x + threadIdx.x;     // 64*4*40*64 = 655,360
  int l  = f & 63;
  int q  = f >> 6;
  int kk = q % KSTEPS;
  int q2 = q / KSTEPS;
  int gt = q2 & 3;
  int r  = q2 >> 2;
  int n  = l & 15;
  int grow = gt * H_ + r * 16 + n;
  int k0 = kk * 32 + (l >> 4) * 8;
  unsigned short o[8];
#pragma unroll
  for (int e = 0; e < 8; ++e) {
    int k = k0 + e;
    float val = (k < I_) ? Wih[(size_t)grow * I_ + k] : Whh[(size_t)grow * H_ + (k - I_)];
    o[e] = f2bf(val);
  }
  *(uint4*)(wpack + (size_t)f * 8) = *(uint4*)o;
  if (kk == 0 && (l >> 4) == 0)
    biasp[(r * 4 + gt) * 16 + n] = bih[grow] + bhh[grow];
}

// ---------------- K1b: pack W_fc [I,H] -> fragment layout ----------------
__global__ void k_pack_wfc(const float* __restrict__ Wfc, unsigned short* __restrict__ wfcp) {
  int f = blockIdx.x * blockDim.x + threadIdx.x;     // 32768
  int l  = f & 63;
  int nt = (f >> 6) & 15;
  int kk = f >> 10;
  int n  = nt * 16 + (l & 15);
  int k0 = kk * 32 + (l >> 4) * 8;
  unsigned short o[8];
#pragma unroll
  for (int e = 0; e < 8; ++e) o[e] = f2bf(Wfc[(size_t)n * H_ + k0 + e]);
  *(uint4*)(wfcp + (size_t)f * 8) = *(uint4*)o;
}

// ---------------- K1c: h0 -> bf16 hbuf [B][H]; zero flags ----------------
__global__ void k_init_h(const float* __restrict__ h0, unsigned short* __restrict__ hbuf,
                         unsigned int* __restrict__ flags) {
  int idx = blockIdx.x * blockDim.x + threadIdx.x;   // 8192
  const float* s = h0 + (size_t)idx * 8;
  unsigned short o[8];
#pragma unroll
  for (int e = 0; e < 8; ++e) o[e] = f2bf(s[e]);
  *(uint4*)(hbuf + (size_t)idx * 8) = *(uint4*)o;
  if (idx < 1024) flags[idx] = 0;   // 4 groups x 64 ranks x 4 wave-flags
}

// ---------------- K2: grouped persistent LSTM recurrence (16 real rows) ----------------
// 256 WGs x 512 threads, 1 WG/CU (84 KB LDS). g = blockIdx&3, r = blockIdx>>2.
// Group g owns batch rows [g*16, g*16+16); rank r owns h-cols [r*16, r*16+16).
// Wave v: gate gt=v&3, K-half kh=v>>2 -> 16 MFMAs (W_hh half in 64 regs);
// kh=0 waves also hold x-part W in 32 regs and compute x(t+1) in shadow.
// hlds: 16 rows x 2048B, XOR-swizzle off^=(row&7)<<4 -> conflict-free b128.
// Gate math 4-way parallel: wave 4+q owns row-group q (rows q*4..q*4+3),
// posts its own flag after its own vmcnt(0) drain. 3 barriers/step.
// Coherence: sc1 write-through h stores into hs[t] (unique addr/step);
// consumers plain cached loads; flags agent-scope stores, sc1 polls.
__global__ void __launch_bounds__(512, 2) k_lstm(
    const unsigned short* __restrict__ xb, const unsigned short* __restrict__ wpack,
    const float* __restrict__ biasp, const float* __restrict__ c0,
    const unsigned short* __restrict__ hbuf, unsigned short* __restrict__ hs,
    unsigned int* __restrict__ flags) {
  __shared__ unsigned short hlds[38912];   // first 32 KB used; sized 76KB -> 1 WG/CU
  __shared__ f32x4 pacc[8][64];            // 8 KB gate partials
  const int tid  = threadIdx.x;
  const int wave = tid >> 6, lane = tid & 63;
  const int g = blockIdx.x & 3, r = blockIdx.x >> 2;
  const int gt = wave & 3, kh = wave >> 2;
  const int q4 = wave - 4;                 // row-group for gate waves (v>=4)

  const uint4* wp4 = (const uint4*)wpack + (size_t)(r * 4 + gt) * (KSTEPS * 64);

  // h-part W (my gate, my K-half): 16 frags = 64 VGPRs
  bf16x8 wb[16];
#pragma unroll
  for (int j = 0; j < 16; ++j)
    wb[j] = __builtin_bit_cast(bf16x8, wp4[(size_t)(8 + kh * 16 + j) * 64 + lane]);
  // x-part W (kh==0 waves): 8 frags = 32 VGPRs
  bf16x8 xwb[8];
  if (kh == 0) {
#pragma unroll
    for (int j = 0; j < 8; ++j)
      xwb[j] = __builtin_bit_cast(bf16x8, wp4[(size_t)j * 64 + lane]);
  }

  const int row   = lane & 15;             // A-fragment row = real batch row
  const int ql16  = (lane >> 4) * 16;      // A-frag k byte offset within slice
  const int rmask = (row & 7) << 4;        // hlds XOR swizzle mask
  const float bv  = (kh == 0) ? biasp[(r * 4 + gt) * 16 + (lane & 15)] : 0.f;
  float creg[4] = {0.f, 0.f, 0.f, 0.f};
  if (wave >= 4 && lane < 16) {
#pragma unroll
    for (int e = 0; e < 4; ++e)
      creg[e] = c0[(size_t)(g * BG + q4 * 4 + e) * H_ + r * 16 + lane];
  }

  f32x4 xacc = {0.f, 0.f, 0.f, 0.f};
  auto computeX = [&](int t) {             // kh==0 waves: pure global+reg, in shadow
    xacc = f32x4{bv, bv, bv, bv};
    const unsigned short* xrow = xb + ((size_t)t * B_ + g * BG + row) * I_ + (lane >> 4) * 8;
#pragma unroll
    for (int kk = 0; kk < 8; ++kk) {
      bf16x8 a = *(const bf16x8*)(xrow + kk * 32);
      xacc = __builtin_amdgcn_mfma_f32_16x16x32_bf16(a, xwb[kk], xacc, 0, 0, 0);
    }
  };
  if (kh == 0) computeX(0);

  for (int t = 0; t < T_; ++t) {
    // ---- wait: wave0 polls 64 ranks x 4 wave-flags (1 dwordx4/lane, sc1) ----
    if (t > 0) {
      if (wave == 0) {
        const uint4* fp = (const uint4*)flags + g * 64 + lane;
        const unsigned target = (unsigned)t;
        int guard = 0;
        for (;;) {
          uint4 v;
          asm volatile("global_load_dwordx4 %0, %1, off sc1\n\ts_waitcnt vmcnt(0)"
                       : "=&v"(v) : "v"(fp) : "memory");
          if (__all(v.x >= target && v.y >= target && v.z >= target && v.w >= target)) break;
          if (++guard > (1 << 20)) break;   // safety: never hard-hang
        }
      }
      __syncthreads();   // A: release; orders poll before h loads
    }

    // ---- stage h_prev rows {wave, wave+8} into swizzled hlds ----
    {
      const unsigned short* s0 =
          (t == 0) ? hbuf + (size_t)(g * BG + wave) * H_ + lane * 8
                   : hs + ((size_t)(t - 1) * B_ + g * BG + wave) * H_ + lane * 8;
      const unsigned short* s1 = s0 + 8 * H_;   // row wave+8
      uint4 a0 = *(const uint4*)s0;
      uint4 a1 = *(const uint4*)(s0 + 512);
      uint4 a2 = *(const uint4*)s1;
      uint4 a3 = *(const uint4*)(s1 + 512);
      char* d0 = (char*)hlds + wave * 2048 + ((lane * 16) ^ (wave << 4));
      *(uint4*)(d0) = a0;
      *(uint4*)(d0 + 1024) = a1;
      char* d1 = d0 + 8 * 2048;                 // row wave+8: same swizzle (&7)
      *(uint4*)(d1) = a2;
      *(uint4*)(d1 + 1024) = a3;
    }
    __syncthreads();   // B: hlds ready

    // ---- 16 MFMAs (W in regs, swizzled h from LDS), 2 independent chains ----
    f32x4 accA = (kh == 0) ? xacc : f32x4{0.f, 0.f, 0.f, 0.f};
    f32x4 accB = {0.f, 0.f, 0.f, 0.f};
    const char* hb = (const char*)hlds + row * 2048 + kh * 1024;
#pragma unroll
    for (int j = 0; j < 16; j += 2) {
      bf16x8 h0f = *(const bf16x8*)(hb + ((j * 64 + ql16) ^ rmask));
      bf16x8 h1f = *(const bf16x8*)(hb + (((j + 1) * 64 + ql16) ^ rmask));
      accA = __builtin_amdgcn_mfma_f32_16x16x32_bf16(h0f, wb[j], accA, 0, 0, 0);
      accB = __builtin_amdgcn_mfma_f32_16x16x32_bf16(h1f, wb[j + 1], accB, 0, 0, 0);
    }
    pacc[wave][lane] = accA + accB;
    __syncthreads();   // C: all partials in LDS

    if (wave >= 4) {
      // ---- gate math, 4-way parallel: wave 4+q owns rows q*4..q*4+3 ----
      unsigned hbits[4] = {0, 0, 0, 0};
      if (lane < 16) {
        f32x4 p0 = pacc[0][q4 * 16 + lane], p4v = pacc[4][q4 * 16 + lane];
        f32x4 p1 = pacc[1][q4 * 16 + lane], p5v = pacc[5][q4 * 16 + lane];
        f32x4 p2 = pacc[2][q4 * 16 + lane], p6v = pacc[6][q4 * 16 + lane];
        f32x4 p3 = pacc[3][q4 * 16 + lane], p7v = pacc[7][q4 * 16 + lane];
#pragma unroll
        for (int e = 0; e < 4; ++e) {
          float gi = p0[e] + p4v[e], gf = p1[e] + p5v[e];
          float gg = p2[e] + p6v[e], go = p3[e] + p7v[e];
          float ig = sigm(gi), fg = sigm(gf), g2 = tanh_fast(gg), og = sigm(go);
          float cn = fg * creg[e] + ig * g2;
          creg[e] = cn;
          hbits[e] = f2bf(og * tanh_fast(cn));
        }
      }
      // pack 4 adjacent cols -> one 8B sc1 store per (row, col-quad)
#pragma unroll
      for (int e = 0; e < 4; ++e) {
        unsigned vpair = hbits[e] | ((unsigned)__shfl_xor((int)hbits[e], 1) << 16);
        unsigned long long vquad = (unsigned long long)vpair |
            ((unsigned long long)(unsigned)__shfl_xor((int)vpair, 2) << 32);
        if (lane < 16 && (lane & 3) == 0) {
          unsigned long long* dst = (unsigned long long*)
              (hs + ((size_t)t * B_ + g * BG + q4 * 4 + e) * H_ + (size_t)r * 16 + lane);
          __hip_atomic_store(dst, vquad, __ATOMIC_RELAXED, __HIP_MEMORY_SCOPE_AGENT);
        }
      }
      asm volatile("s_waitcnt vmcnt(0)" ::: "memory");   // own stores drained
      if (lane == 0)
        __hip_atomic_store(flags + g * 256 + r * 4 + q4, (unsigned)(t + 1),
                           __ATOMIC_RELAXED, __HIP_MEMORY_SCOPE_AGENT);
    } else if (t + 1 < T_) {
      computeX(t + 1);   // x-part shadow for the coming poll window
    }
  }
}

// ---------------- K3: out[t,b,:] = hs[t,b,:] @ W_fc^T + b_fc ----------------
__global__ void k_fc(const unsigned short* __restrict__ hs, const unsigned short* __restrict__ wfcp,
                     const float* __restrict__ bfc, float* __restrict__ out) {
  const int bm = blockIdx.x >> 2, bn = blockIdx.x & 3;
  const int tid = threadIdx.x, wave = tid >> 6, lane = tid & 63;
  const int rr   = bm * 64 + wave * 16 + (lane & 15);
  const int kOff = (lane >> 4) * 8;
  const int nb   = bn * 4;
  f32x4 acc[4];
#pragma unroll
  for (int nt = 0; nt < 4; ++nt) {
    float bvv = bfc[(nb + nt) * 16 + (lane & 15)];
    acc[nt] = {bvv, bvv, bvv, bvv};
  }
  const unsigned short* arow = hs + (size_t)rr * H_ + kOff;
#pragma unroll 2
  for (int kk = 0; kk < 32; ++kk) {
    bf16x8 a = *(const bf16x8*)(arow + kk * 32);
#pragma unroll
    for (int nt = 0; nt < 4; ++nt) {
      bf16x8 b = *(const bf16x8*)(wfcp + ((size_t)(kk * 16 + nb + nt) * 64 + lane) * 8);
      acc[nt] = __builtin_amdgcn_mfma_f32_16x16x32_bf16(a, b, acc[nt], 0, 0, 0);
    }
  }
  const int ro = bm * 64 + wave * 16 + (lane >> 4) * 4;
#pragma unroll
  for (int nt = 0; nt < 4; ++nt)
#pragma unroll
    for (int e = 0; e < 4; ++e)
      out[(size_t)(ro + e) * I_ + (nb + nt) * 16 + (lane & 15)] = acc[nt][e];
}

// ---------------- launcher ----------------
extern "C" void kernel_launch(void* const* d_in, const int* in_sizes, int n_in,
                              void* d_out, int out_size, void* d_ws, size_t ws_size,
                              hipStream_t stream) {
  const float* x   = (const float*)d_in[0];
  const float* h0  = (const float*)d_in[1];
  const float* c0  = (const float*)d_in[2];
  const float* Wih = (const float*)d_in[3];
  const float* Whh = (const float*)d_in[4];
  const float* bih = (const float*)d_in[5];
  const float* bhh = (const float*)d_in[6];
  const float* Wfc = (const float*)d_in[7];
  const float* bfc = (const float*)d_in[8];
  float* out = (float*)d_out;

  char* ws = (char*)d_ws;
  unsigned short* xb    = (unsigned short*)(ws + 0);           // 16,777,216
  unsigned short* hsb   = (unsigned short*)(ws + 16777216);    // 67,108,864
  unsigned short* wpk   = (unsigned short*)(ws + 83886080);    // 10,485,760
  float*          biasp = (float*)        (ws + 94371840);     //     16,384
  unsigned short* wfcp  = (unsigned short*)(ws + 94388224);    //    524,288
  unsigned short* hbuf  = (unsigned short*)(ws + 94912512);    //    262,144
  unsigned int*   flg   = (unsigned int*)  (ws + 95174656);    //      4,096

  k_pack_x  <<<4096, 256, 0, stream>>>(x, xb);
  k_pack_w  <<<2560, 256, 0, stream>>>(Wih, Whh, bih, bhh, wpk, biasp);
  k_pack_wfc<<<128,  256, 0, stream>>>(Wfc, wfcp);
  k_init_h  <<<32,   256, 0, stream>>>(h0, hbuf, flg);
  k_lstm    <<<NWG,  512, 0, stream>>>(xb, wpk, biasp, c0, hbuf, hsb, flg);
  k_fc      <<<2048, 256, 0, stream>>>(hsb, wfcp, bfc, out);
}

// Round 15
// 2243.575 us; speedup vs baseline: 1.4215x; 1.4215x over previous
//
#include <hip/hip_runtime.h>
#include <hip/hip_bf16.h>

// Problem constants
#define B_    64
#define T_    512
#define I_    256
#define H_    1024
#define KSTEPS 40          // (I_+H_)/32 slices
#define NGRP  8            // batch groups (blockIdx&7 -> round-robin = 1 XCD each)
#define BG    8            // batch rows per group
#define RPG   32           // ranks (WGs) per group
#define NWG   256          // total recurrence WGs

typedef __bf16 bf16x8 __attribute__((ext_vector_type(8)));
typedef float  f32x4  __attribute__((ext_vector_type(4)));

__device__ __forceinline__ unsigned short f2bf(float f) {
  unsigned u = __builtin_bit_cast(unsigned, f);
  u += 0x7FFFu + ((u >> 16) & 1u);       // round-to-nearest-even
  return (unsigned short)(u >> 16);
}
__device__ __forceinline__ float sigm(float x) { return 1.0f / (1.0f + __expf(-x)); }
__device__ __forceinline__ float tanh_fast(float x) {
  float ax = fabsf(x);
  float e  = __expf(-2.0f * ax);
  float t  = (1.0f - e) / (1.0f + e);
  return x < 0.0f ? -t : t;
}

// ---------------- K0: x [B,T,I] f32 -> xb [T,B,I] bf16 ----------------
__global__ void k_pack_x(const float* __restrict__ x, unsigned short* __restrict__ xb) {
  int idx = blockIdx.x * blockDim.x + threadIdx.x;   // B*T*I/8 = 1,048,576
  int ic = idx & 31;
  int t  = (idx >> 5) & 511;
  int b  = idx >> 14;
  const float* src = x + ((size_t)b * T_ + t) * I_ + ic * 8;
  float4 f0 = *(const float4*)src;
  float4 f1 = *(const float4*)(src + 4);
  unsigned short o[8] = {f2bf(f0.x), f2bf(f0.y), f2bf(f0.z), f2bf(f0.w),
                         f2bf(f1.x), f2bf(f1.y), f2bf(f1.z), f2bf(f1.w)};
  *(uint4*)(xb + ((size_t)t * B_ + b) * I_ + ic * 8) = *(uint4*)o;
}

// ---------------- K1a: pack W into per-(rank,wave) B-fragment layout ----------------
// wave v of rank r owns gate tile: gate = v>>1, cols r*32 + (v&1)*16 + (lane&15).
// layout: [((r*8+v)*40 + kk)*64 + lane] (16B frag), k = kk*32 + (lane>>4)*8 + e.
__global__ void k_pack_w(const float* __restrict__ Wih, const float* __restrict__ Whh,
                         const float* __restrict__ bih, const float* __restrict__ bhh,
                         unsigned short* __restrict__ wpack, float* __restrict__ biasp) {
  int f = blockIdx.x * blockDim.x + threadIdx.x;     // 32*8*40*64 = 655,360
  int l  = f & 63;
  int q  = f >> 6;
  int kk = q % KSTEPS;
  int q2 = q / KSTEPS;
  int v  = q2 & 7;
  int r  = q2 >> 3;
  int gate = v >> 1;
  int col  = r * 32 + (v & 1) * 16 + (l & 15);
  int grow = gate * H_ + col;
  int k0 = kk * 32 + (l >> 4) * 8;
  unsigned short o[8];
#pragma unroll
  for (int e = 0; e < 8; ++e) {
    int k = k0 + e;
    float val = (k < I_) ? Wih[(size_t)grow * I_ + k] : Whh[(size_t)grow * H_ + (k - I_)];
    o[e] = f2bf(val);
  }
  *(uint4*)(wpack + (size_t)f * 8) = *(uint4*)o;
  if (kk == 0 && (l >> 4) == 0)
    biasp[(r * 8 + v) * 16 + (l & 15)] = bih[grow] + bhh[grow];
}

// ---------------- K1b: pack W_fc [I,H] -> fragment layout ----------------
__global__ void k_pack_wfc(const float* __restrict__ Wfc, unsigned short* __restrict__ wfcp) {
  int f = blockIdx.x * blockDim.x + threadIdx.x;     // 32768
  int l  = f & 63;
  int nt = (f >> 6) & 15;
  int kk = f >> 10;
  int n  = nt * 16 + (l & 15);
  int k0 = kk * 32 + (l >> 4) * 8;
  unsigned short o[8];
#pragma unroll
  for (int e = 0; e < 8; ++e) o[e] = f2bf(Wfc[(size_t)n * H_ + k0 + e]);
  *(uint4*)(wfcp + (size_t)f * 8) = *(uint4*)o;
}

// ---------------- K1c: h0 -> bf16 hbuf [B][H]; zero flags ----------------
__global__ void k_init_h(const float* __restrict__ h0, unsigned short* __restrict__ hbuf,
                         unsigned int* __restrict__ flags) {
  int idx = blockIdx.x * blockDim.x + threadIdx.x;   // 8192
  const float* s = h0 + (size_t)idx * 8;
  unsigned short o[8];
#pragma unroll
  for (int e = 0; e < 8; ++e) o[e] = f2bf(s[e]);
  *(uint4*)(hbuf + (size_t)idx * 8) = *(uint4*)o;
  if (idx < 2048) flags[idx] = 0;   // 8 groups x 32 ranks x 8 wave-flags
}

// ---------------- K2: grouped persistent LSTM recurrence ----------------
// 256 WGs x 512 threads, 1 WG/CU (88 KB LDS). g = blockIdx&7 (round-robin =>
// XCD-local, heuristic only), rank r = blockIdx>>3. Group g owns batch rows
// [g*8, g*8+8); rank r owns h-cols [r*32, r*32+32). Wave v computes gate tile
// (gate=v>>1, half=v&1) with W_hh in REGISTERS (128/lane).
// hlds: 8 rows x 2048B, XOR swizzle off^=(row<<4): any 16 consecutive lanes
// (8 unique rows, dup broadcast) hit all 32 banks exactly once -> conflict-free.
// Tail: wave v does gate math for ROW v x all 32 cols (col = lane), c scalar,
// h-store = one coalesced 64B line, per-wave flag after own vmcnt(0) drain.
// Coherence (placement-independent): sc1 write-through h stores into hs[t]
// (unique addr/step -> no stale lines); consumers plain cached loads; flags
// agent-scope stores, sc1 polls. 3 barriers/step.
__global__ void __launch_bounds__(512, 2) k_lstm(
    const unsigned short* __restrict__ xb, const unsigned short* __restrict__ wpack,
    const float* __restrict__ biasp, const float* __restrict__ c0,
    const unsigned short* __restrict__ hbuf, unsigned short* __restrict__ hs,
    unsigned int* __restrict__ flags) {
  __shared__ unsigned short hlds[8192];    // 16 KB staged h (8 rows x 2048B, swizzled)
  __shared__ f32x4 pacc[8][64];            // 8 KB gate partials
  __shared__ uint4 xlds[8 * 8 * 64];       // 64 KB x-part W
  const int tid  = threadIdx.x;
  const int wave = tid >> 6, lane = tid & 63;
  const int g = blockIdx.x & 7, r = blockIdx.x >> 3;

  const uint4* wp4 = (const uint4*)wpack;
  { // x-part W (kk 0..7, all 8 tiles of this rank) into LDS
    for (int i = tid; i < 4096; i += 512) {
      int v = i >> 9, kk = (i >> 6) & 7, l = i & 63;
      xlds[i] = wp4[(size_t)((r * 8 + v) * KSTEPS + kk) * 64 + l];
    }
  }
  // h-part W (kk 8..39) for MY gate tile into registers: 128 VGPRs
  bf16x8 wr[32];
#pragma unroll
  for (int j = 0; j < 32; ++j)
    wr[j] = __builtin_bit_cast(bf16x8, wp4[(size_t)((r * 8 + wave) * KSTEPS + 8 + j) * 64 + lane]);

  const int row   = (lane & 15) & 7;       // A-frag batch row (2x dup in M)
  const int qo    = (lane >> 4) * 16;      // A-frag k byte offset within slice
  const int rx    = row << 4;              // hlds XOR swizzle mask
  const float bv  = biasp[(r * 8 + wave) * 16 + (lane & 15)];
  float creg = 0.f;                        // c-state: row=wave, col=r*32+lane
  if (lane < 32)
    creg = c0[(size_t)(g * BG + wave) * H_ + r * 32 + lane];

  __syncthreads();   // xlds ready

  f32x4 xacc;
  auto computeX = [&](int t) {   // post-flag shadow: x loads + LDS W + 8 MFMA
    xacc = f32x4{bv, bv, bv, bv};
    const unsigned short* xrow = xb + ((size_t)t * B_ + g * BG + row) * I_ + (lane >> 4) * 8;
#pragma unroll
    for (int kk = 0; kk < 8; ++kk) {
      bf16x8 a = *(const bf16x8*)(xrow + kk * 32);
      bf16x8 b = __builtin_bit_cast(bf16x8, xlds[(wave * 8 + kk) * 64 + lane]);
      xacc = __builtin_amdgcn_mfma_f32_16x16x32_bf16(a, b, xacc, 0, 0, 0);
    }
  };
  computeX(0);

  for (int t = 0; t < T_; ++t) {
    // ---- wait: wave0 polls this group's 256 wave-flags (1 dwordx4/lane, sc1) ----
    if (t > 0) {
      if (wave == 0) {
        const uint4* fp = (const uint4*)flags + g * 64 + lane;
        const unsigned target = (unsigned)t;
        int guard = 0;
        for (;;) {
          uint4 v;
          asm volatile("global_load_dwordx4 %0, %1, off sc1\n\ts_waitcnt vmcnt(0)"
                       : "=&v"(v) : "v"(fp) : "memory");
          if (__all(v.x >= target && v.y >= target && v.z >= target && v.w >= target)) break;
          if (++guard > (1 << 20)) break;   // safety: never hard-hang
        }
      }
      __syncthreads();   // A: release all waves; orders poll before h loads
    }

    // ---- stage h_prev row=wave (2 KB) into swizzled hlds ----
    {
      const unsigned short* src =
          (t == 0) ? hbuf + (size_t)(g * BG + wave) * H_ + lane * 8
                   : hs + ((size_t)(t - 1) * B_ + g * BG + wave) * H_ + lane * 8;
      uint4 a0 = *(const uint4*)src;
      uint4 a1 = *(const uint4*)(src + 512);
      char* d0 = (char*)hlds + wave * 2048 + ((lane * 16) ^ (wave << 4));
      *(uint4*)d0 = a0;
      *(uint4*)(d0 + 1024) = a1;
    }
    __syncthreads();   // B: hlds ready

    // ---- 32 MFMAs (W in regs, swizzled h from LDS), 2 independent chains ----
    f32x4 accA = xacc, accB = {0.f, 0.f, 0.f, 0.f};
    const char* hb = (const char*)hlds + row * 2048;
#pragma unroll
    for (int j = 0; j < 32; j += 2) {
      bf16x8 h0f = *(const bf16x8*)(hb + ((j * 64 + qo) ^ rx));
      bf16x8 h1f = *(const bf16x8*)(hb + (((j + 1) * 64 + qo) ^ rx));
      accA = __builtin_amdgcn_mfma_f32_16x16x32_bf16(h0f, wr[j], accA, 0, 0, 0);
      accB = __builtin_amdgcn_mfma_f32_16x16x32_bf16(h1f, wr[j + 1], accB, 0, 0, 0);
    }
    pacc[wave][lane] = accA + accB;
    __syncthreads();   // C: all gate tiles in LDS

    // ---- tail: wave v = ROW v, col = lane (0..31); zero extra barriers ----
    unsigned hbp = 0;
    if (lane < 32) {
      const int c  = lane;
      const int lp = ((wave & 4) << 2) | (c & 15);   // D-frag lane for row=wave
      const int e  = wave & 3;
      const int hf = c >> 4;
      const float* pf = (const float*)pacc;
      float gi = pf[((0 + hf) * 64 + lp) * 4 + e];
      float gf = pf[((2 + hf) * 64 + lp) * 4 + e];
      float gg = pf[((4 + hf) * 64 + lp) * 4 + e];
      float go = pf[((6 + hf) * 64 + lp) * 4 + e];
      float ig = sigm(gi), fg = sigm(gf), g2 = tanh_fast(gg), og = sigm(go);
      float cn = fg * creg + ig * g2;
      creg = cn;
      hbp = f2bf(og * tanh_fast(cn));
    }
    // pack 4 cols/8B; 8 stores cover ONE 64B line (coalesced full-line write)
    {
      unsigned vpair = hbp | ((unsigned)__shfl_xor((int)hbp, 1) << 16);
      unsigned long long vquad = (unsigned long long)vpair |
          ((unsigned long long)(unsigned)__shfl_xor((int)vpair, 2) << 32);
      if (lane < 32 && (lane & 3) == 0) {
        unsigned long long* dst = (unsigned long long*)
            (hs + ((size_t)t * B_ + g * BG + wave) * H_ + (size_t)r * 32 + lane);
        __hip_atomic_store(dst, vquad, __ATOMIC_RELAXED, __HIP_MEMORY_SCOPE_AGENT);
      }
    }
    asm volatile("s_waitcnt vmcnt(0)" ::: "memory");   // own line drained
    if (lane == 0)
      __hip_atomic_store(flags + g * 256 + r * 8 + wave, (unsigned)(t + 1),
                         __ATOMIC_RELAXED, __HIP_MEMORY_SCOPE_AGENT);

    // next step's x-part overlaps the coming poll window
    if (t + 1 < T_) computeX(t + 1);
  }
}

// ---------------- K3: out[t,b,:] = hs[t,b,:] @ W_fc^T + b_fc ----------------
__global__ void k_fc(const unsigned short* __restrict__ hs, const unsigned short* __restrict__ wfcp,
                     const float* __restrict__ bfc, float* __restrict__ out) {
  const int bm = blockIdx.x >> 2, bn = blockIdx.x & 3;
  const int tid = threadIdx.x, wave = tid >> 6, lane = tid & 63;
  const int rr   = bm * 64 + wave * 16 + (lane & 15);
  const int kOff = (lane >> 4) * 8;
  const int nb   = bn * 4;
  f32x4 acc[4];
#pragma unroll
  for (int nt = 0; nt < 4; ++nt) {
    float bvv = bfc[(nb + nt) * 16 + (lane & 15)];
    acc[nt] = {bvv, bvv, bvv, bvv};
  }
  const unsigned short* arow = hs + (size_t)rr * H_ + kOff;
#pragma unroll 2
  for (int kk = 0; kk < 32; ++kk) {
    bf16x8 a = *(const bf16x8*)(arow + kk * 32);
#pragma unroll
    for (int nt = 0; nt < 4; ++nt) {
      bf16x8 b = *(const bf16x8*)(wfcp + ((size_t)(kk * 16 + nb + nt) * 64 + lane) * 8);
      acc[nt] = __builtin_amdgcn_mfma_f32_16x16x32_bf16(a, b, acc[nt], 0, 0, 0);
    }
  }
  const int ro = bm * 64 + wave * 16 + (lane >> 4) * 4;
#pragma unroll
  for (int nt = 0; nt < 4; ++nt)
#pragma unroll
    for (int e = 0; e < 4; ++e)
      out[(size_t)(ro + e) * I_ + (nb + nt) * 16 + (lane & 15)] = acc[nt][e];
}

// ---------------- launcher ----------------
extern "C" void kernel_launch(void* const* d_in, const int* in_sizes, int n_in,
                              void* d_out, int out_size, void* d_ws, size_t ws_size,
                              hipStream_t stream) {
  const float* x   = (const float*)d_in[0];
  const float* h0  = (const float*)d_in[1];
  const float* c0  = (const float*)d_in[2];
  const float* Wih = (const float*)d_in[3];
  const float* Whh = (const float*)d_in[4];
  const float* bih = (const float*)d_in[5];
  const float* bhh = (const float*)d_in[6];
  const float* Wfc = (const float*)d_in[7];
  const float* bfc = (const float*)d_in[8];
  float* out = (float*)d_out;

  char* ws = (char*)d_ws;
  unsigned short* xb    = (unsigned short*)(ws + 0);           // 16,777,216
  unsigned short* hsb   = (unsigned short*)(ws + 16777216);    // 67,108,864
  unsigned short* wpk   = (unsigned short*)(ws + 83886080);    // 10,485,760
  float*          biasp = (float*)        (ws + 94371840);     //     16,384
  unsigned short* wfcp  = (unsigned short*)(ws + 94388224);    //    524,288
  unsigned short* hbuf  = (unsigned short*)(ws + 94912512);    //    131,072
  unsigned int*   flg   = (unsigned int*)  (ws + 95043584);    //      8,192

  k_pack_x  <<<4096, 256, 0, stream>>>(x, xb);
  k_pack_w  <<<2560, 256, 0, stream>>>(Wih, Whh, bih, bhh, wpk, biasp);
  k_pack_wfc<<<128,  256, 0, stream>>>(Wfc, wfcp);
  k_init_h  <<<32,   256, 0, stream>>>(h0, hbuf, flg);
  k_lstm    <<<NWG,  512, 0, stream>>>(xb, wpk, biasp, c0, hbuf, hsb, flg);
  k_fc      <<<2048, 256, 0, stream>>>(hsb, wfcp, bfc, out);
}